// Round 10
// baseline (477.687 us; speedup 1.0000x reference)
//
#include <hip/hip_runtime.h>

typedef __attribute__((ext_vector_type(8))) short short8;
typedef __attribute__((ext_vector_type(4))) float floatx4;
typedef __attribute__((ext_vector_type(4))) unsigned short ushort4v;

#define H_ 12
#define S_ 2048
#define D_ 768
#define DFF_ 3072
#define DH_ 64
#define BH_ 48
#define M_ 8192
// 0.125 (1/sqrt(64)) * log2(e): QK^T lands in log2-domain
#define QSCALE 0.180336880f

// HW exp2/log2 via compiler-known trans intrinsics (hazard nops handled by compiler;
// raw inline-asm v_exp_f32 raced its consumer -> NaN in round 5).
#if defined(__has_builtin)
#if __has_builtin(__builtin_amdgcn_exp2f)
#define EXP2V(x) __builtin_amdgcn_exp2f(x)
#endif
#if __has_builtin(__builtin_amdgcn_logf)
#define LOG2V(x) __builtin_amdgcn_logf(x)
#endif
#endif
#ifndef EXP2V
#define EXP2V(x) exp2f(x)
#endif
#ifndef LOG2V
#define LOG2V(x) log2f(x)
#endif

__device__ __forceinline__ unsigned short f2bf(float f) {
  union { float f; unsigned int u; } a; a.f = f;
  return (unsigned short)((a.u + 0x7FFFu + ((a.u >> 16) & 1u)) >> 16);
}
__device__ __forceinline__ unsigned int cvtpk_bf16(float lo, float hi) {
  unsigned int u;
  asm("v_cvt_pk_bf16_f32 %0, %1, %2" : "=v"(u) : "v"(lo), "v"(hi));
  return u;
}

// async global->LDS. LDS base wave-uniform (HW adds lane*size).
__device__ __forceinline__ void glds16(const void* g, void* l) {
  __builtin_amdgcn_global_load_lds(
      (const __attribute__((address_space(1))) void*)(unsigned long long)(size_t)g,
      (__attribute__((address_space(3))) void*)(unsigned int)(size_t)l, 16, 0, 0);
}
__device__ __forceinline__ void glds4(const void* g, void* l) {
  __builtin_amdgcn_global_load_lds(
      (const __attribute__((address_space(1))) void*)(unsigned long long)(size_t)g,
      (__attribute__((address_space(3))) void*)(unsigned int)(size_t)l, 4, 0, 0);
}

// XCD-chunked bijective swizzle (nwg % 8 == 0).
__device__ __forceinline__ int swz8(int lin, int nwg) {
  return (lin & 7) * (nwg >> 3) + (lin >> 3);
}

// ---------------- fp32 -> bf16 convert ----------------
__global__ __launch_bounds__(256) void cvt_bf16(const float* __restrict__ in,
                                                unsigned short* __restrict__ out) {
  size_t i = ((size_t)blockIdx.x * 256 + threadIdx.x) * 4;
  floatx4 v = *reinterpret_cast<const floatx4*>(in + i);
  ushort4v o;
  o[0] = f2bf(v[0]); o[1] = f2bf(v[1]); o[2] = f2bf(v[2]); o[3] = f2bf(v[3]);
  *reinterpret_cast<ushort4v*>(out + i) = o;
}

// ---------------- weight transpose fp32[K][N] -> bf16[N][K] ----------------
__global__ __launch_bounds__(256) void wtrans(const float* __restrict__ W,
                                              unsigned short* __restrict__ Wt,
                                              int K, int N) {
  __shared__ float t[64][65];
  const int n0 = blockIdx.x * 64, k0 = blockIdx.y * 64;
  const int tid = threadIdx.x;
#pragma unroll
  for (int i = 0; i < 16; ++i) {
    int idx = tid + 256 * i;
    int kl = idx >> 6, nl = idx & 63;
    t[kl][nl] = W[(size_t)(k0 + kl) * N + n0 + nl];
  }
  __syncthreads();
#pragma unroll
  for (int i = 0; i < 16; ++i) {
    int idx = tid + 256 * i;
    int nl = idx >> 6, kl = idx & 63;
    Wt[(size_t)(n0 + nl) * K + k0 + kl] = f2bf(t[kl][nl]);
  }
}

// -------- per-head transpose: kvb[(b*S+kk)*D + h*64+d] -> kvtb[bh][d][kk] --------
__global__ __launch_bounds__(256) void kvtrans(const unsigned short* __restrict__ KVb,
                                               unsigned short* __restrict__ KVTb) {
  __shared__ unsigned short t[64][72];
  const int kk0 = blockIdx.x * 64;
  const int bh = blockIdx.y, b = bh / H_, h = bh % H_;
  const size_t xbase = ((size_t)b * S_) * D_ + h * DH_;
  const int tid = threadIdx.x;
#pragma unroll
  for (int i = 0; i < 16; ++i) {
    int idx = tid + 256 * i;
    int kl = idx >> 6, d = idx & 63;
    t[kl][d] = KVb[xbase + (size_t)(kk0 + kl) * D_ + d];
  }
  __syncthreads();
  const size_t tb = (size_t)bh * DH_ * S_;
#pragma unroll
  for (int i = 0; i < 16; ++i) {
    int idx = tid + 256 * i;
    int d = idx >> 6, kl = idx & 63;
    KVTb[tb + (size_t)d * S_ + kk0 + kl] = t[kl][d];
  }
}

// ---- bf16 GEMM: C[M][N] = A[M][K] * Bt[N][K]^T; tile 128 x BN (BN in {64,128}) ----
template <int EPI, int OUTBF, int BN>
__global__ __launch_bounds__(256, 2) void gemm128(const unsigned short* __restrict__ A,
                                                  const unsigned short* __restrict__ Bt,
                                                  const float* __restrict__ bias,
                                                  float scale, void* __restrict__ C0,
                                                  void* __restrict__ C1,
                                                  int M, int N, int K, int lda) {
  constexpr int FN = BN / 32;       // B-frags per wave (col dir)
  constexpr int BITER = BN / 32;    // staging iters for Bs (BN*8/256)
  __shared__ unsigned short As[128 * 64];
  __shared__ unsigned short Bs[BN * 64];
  const int tid = threadIdx.x;
  const int l = tid & 63, w = tid >> 6;
  const int wm = w >> 1, wn = w & 1;
  const int lrow = l & 15, lk = l >> 4;
  int lin = (blockIdx.z * gridDim.y + blockIdx.y) * gridDim.x + blockIdx.x;
  int nwg = gridDim.x * gridDim.y * gridDim.z;
  int s = swz8(lin, nwg);
  int xt = s % gridDim.x;
  int rest = s / gridDim.x;
  int yt = rest % gridDim.y;
  int zt = rest / gridDim.y;
  const unsigned short* Ao = A + (size_t)zt * K;
  const unsigned short* Bo = Bt + (size_t)zt * K;
  const int m0 = yt * 128, n0 = xt * BN;
  floatx4 acc[4][FN] = {};
  for (int k0 = 0; k0 < K; k0 += 64) {
    __syncthreads();
#pragma unroll
    for (int i = 0; i < 4; ++i) {
      int idx = w * 64 + i * 256 + l;
      int row = idx >> 3, c8 = idx & 7;
      int sc = (c8 ^ (row & 7)) << 3;
      glds16(Ao + (size_t)(m0 + row) * lda + k0 + sc, As + (size_t)(w * 64 + i * 256) * 8);
    }
#pragma unroll
    for (int i = 0; i < BITER; ++i) {
      int idx = w * 64 + i * 256 + l;
      int row = idx >> 3, c8 = idx & 7;
      int sc = (c8 ^ (row & 7)) << 3;
      glds16(Bo + (size_t)(n0 + row) * lda + k0 + sc, Bs + (size_t)(w * 64 + i * 256) * 8);
    }
    __syncthreads();
#pragma unroll
    for (int ks = 0; ks < 2; ++ks) {
      short8 af[4], bfr[FN];
#pragma unroll
      for (int f = 0; f < 4; ++f) {
        int ar = wm * 64 + f * 16 + lrow;
        af[f] = *reinterpret_cast<const short8*>(
            &As[ar * 64 + (((ks * 4 + lk) ^ (ar & 7)) << 3)]);
      }
#pragma unroll
      for (int f = 0; f < FN; ++f) {
        int br = wn * (BN / 2) + f * 16 + lrow;
        bfr[f] = *reinterpret_cast<const short8*>(
            &Bs[br * 64 + (((ks * 4 + lk) ^ (br & 7)) << 3)]);
      }
#pragma unroll
      for (int fm = 0; fm < 4; ++fm)
#pragma unroll
        for (int fn = 0; fn < FN; ++fn)
          acc[fm][fn] =
              __builtin_amdgcn_mfma_f32_16x16x32_bf16(af[fm], bfr[fn], acc[fm][fn], 0, 0, 0);
    }
  }
#pragma unroll
  for (int fm = 0; fm < 4; ++fm) {
#pragma unroll
    for (int fn = 0; fn < FN; ++fn) {
      int col = n0 + wn * (BN / 2) + fn * 16 + lrow;
#pragma unroll
      for (int r = 0; r < 4; ++r) {
        int row = m0 + wm * 64 + fm * 16 + lk * 4 + r;
        float v = acc[fm][fn][r];
        if (EPI == 3) {
          if (col < 768)
            ((unsigned short*)C0)[(size_t)row * 768 + col] = f2bf(v * scale);
          else
            ((unsigned short*)C1)[(size_t)row * 768 + col - 768] = f2bf(v);
        } else {
          v = v * scale + ((EPI > 0) ? bias[col] : 0.0f);
          if (EPI == 1) v = fmaxf(v, 0.0f);
          void* Cz = zt ? C1 : C0;
          if (OUTBF) ((unsigned short*)Cz)[(size_t)row * N + col] = f2bf(v);
          else ((float*)Cz)[(size_t)row * N + col] = v;
        }
      }
    }
  }
}

// ------ column softmax denominators (log2 domain): lnl[k] = -log2(sum_q 2^w2[q,k]) ------
template <bool CAUSAL>
__global__ __launch_bounds__(256, 4) void colsum(const unsigned short* __restrict__ Qb,
                                                 const unsigned short* __restrict__ KVb,
                                                 float* __restrict__ lnl) {
  __shared__ unsigned short kvs[64 * 64];
  __shared__ float lred[4][64];
  const int tid = threadIdx.x;
  const int l = tid & 63, w = tid >> 6;
  const int lrow = l & 15, lk = l >> 4;
  const int sw = swz8(blockIdx.x, 32 * BH_);
  const int bh = sw >> 5, kt = sw & 31;
  const int kk0 = kt * 64;
  const int b = bh / H_, h = bh % H_;
  const size_t xbase = ((size_t)b * S_) * D_ + h * DH_;
#pragma unroll
  for (int i = 0; i < 2; ++i) {
    int idx = w * 64 + i * 256 + l;
    int row = idx >> 3, c8 = idx & 7;
    glds16(KVb + xbase + (size_t)(kk0 + row) * D_ + ((c8 ^ (row & 7)) << 3),
           kvs + (size_t)(w * 64 + i * 256) * 8);
  }
  __syncthreads();
  short8 bkv[4][2];
#pragma unroll
  for (int kkf = 0; kkf < 4; ++kkf)
#pragma unroll
    for (int s = 0; s < 2; ++s) {
      int br = kkf * 16 + lrow;
      bkv[kkf][s] = *reinterpret_cast<const short8*>(
          &kvs[br * 64 + (((s * 4 + lk) ^ (br & 7)) << 3)]);
    }
  float lrun[4] = {0.0f, 0.0f, 0.0f, 0.0f};
  const int qbase = CAUSAL ? kk0 : 0;
  const int ntiles = (S_ - qbase) >> 4;
  // software-pipelined Q loads (one tile ahead)
  short8 aqn[2];
  if (w < ntiles) {
    const int q0 = qbase + w * 16;
#pragma unroll
    for (int s = 0; s < 2; ++s)
      aqn[s] = *reinterpret_cast<const short8*>(
          &Qb[xbase + (size_t)(q0 + lrow) * D_ + s * 32 + lk * 8]);
  }
  for (int t = w; t < ntiles; t += 4) {
    const int q0 = qbase + t * 16;
    const bool maskt = CAUSAL && (q0 < kk0 + 64);
    short8 aq0 = aqn[0], aq1 = aqn[1];
    if (t + 4 < ntiles) {
      const int qn = qbase + (t + 4) * 16;
#pragma unroll
      for (int s = 0; s < 2; ++s)
        aqn[s] = *reinterpret_cast<const short8*>(
            &Qb[xbase + (size_t)(qn + lrow) * D_ + s * 32 + lk * 8]);
    }
#pragma unroll
    for (int kkf = 0; kkf < 4; ++kkf) {
      floatx4 sf = {};
      sf = __builtin_amdgcn_mfma_f32_16x16x32_bf16(aq0, bkv[kkf][0], sf, 0, 0, 0);
      sf = __builtin_amdgcn_mfma_f32_16x16x32_bf16(aq1, bkv[kkf][1], sf, 0, 0, 0);
      const int kkg = kk0 + kkf * 16 + lrow;
      float lacc = 0.0f;
      if (maskt) {
#pragma unroll
        for (int r = 0; r < 4; ++r) {
          int qg = q0 + lk * 4 + r;
          lacc += (kkg <= qg) ? EXP2V(sf[r]) : 0.0f;
        }
      } else {
#pragma unroll
        for (int r = 0; r < 4; ++r) lacc += EXP2V(sf[r]);
      }
      lrun[kkf] += lacc;
    }
  }
#pragma unroll
  for (int kkf = 0; kkf < 4; ++kkf) {
    float lv = lrun[kkf];
    lv += __shfl_xor(lv, 16, 64);
    lv += __shfl_xor(lv, 32, 64);
    if (l < 16) lred[w][kkf * 16 + l] = lv;
  }
  __syncthreads();
  if (tid < 64) {
    float lv = lred[0][tid] + lred[1][tid] + lred[2][tid] + lred[3][tid];
    lnl[(size_t)bh * S_ + kk0 + tid] = -LOG2V(lv);  // negated: attnpv acc-init uses it raw
  }
}

// ---- attention PV: swapped QK^T (C[kk][q]) + cvt_pk packing; dbuf + counted vmcnt ----
template <bool CAUSAL>
__global__ __launch_bounds__(256, 3) void attnpv(const unsigned short* __restrict__ Qb,
                                                 const unsigned short* __restrict__ KVb,
                                                 const unsigned short* __restrict__ KVTb,
                                                 const float* __restrict__ lnl,
                                                 float* __restrict__ Opre) {
  __shared__ unsigned short kvs[2][64 * 64];
  __shared__ unsigned short kvts[2][64 * 64];
  __shared__ float slnl[2][4][64];
  __shared__ unsigned short ps[4][32 * 64];
  const int tid = threadIdx.x;
  const int l = tid & 63, w = tid >> 6;
  const int lrow = l & 15, lk = l >> 4;
  const int sw = swz8(blockIdx.x, 16 * BH_);
  const int bh = sw >> 4, qtr = sw & 15;
  const int qt = CAUSAL ? (15 - qtr) : qtr;  // heavy blocks dispatch first
  const int q0 = qt * 128;
  const int wr = w * 32;
  const int b = bh / H_, h = bh % H_;
  const size_t xbase = ((size_t)b * S_) * D_ + h * DH_;
  const size_t tbase = (size_t)bh * DH_ * S_;
  const float* lnlb = lnl + (size_t)bh * S_;

  // exactly 5 VMEM ops per STAGE per thread: 2 kvs + 2 kvts + 1 slnl
  auto STAGE = [&](int buf, int t) {
    const int kk0 = t * 64;
#pragma unroll
    for (int i = 0; i < 2; ++i) {
      int idx = w * 64 + i * 256 + l;
      int row = idx >> 3, c8 = idx & 7;
      int sc = (c8 ^ (row & 7)) << 3;
      glds16(KVb + xbase + (size_t)(kk0 + row) * D_ + sc,
             &kvs[buf][(size_t)(w * 64 + i * 256) * 8]);
      glds16(KVTb + tbase + (size_t)row * S_ + kk0 + sc,
             &kvts[buf][(size_t)(w * 64 + i * 256) * 8]);
    }
    glds4(lnlb + kk0 + l, &slnl[buf][w][0]);
  };

  short8 aq[2][2];
#pragma unroll
  for (int fm = 0; fm < 2; ++fm)
#pragma unroll
    for (int s = 0; s < 2; ++s)
      aq[fm][s] = *reinterpret_cast<const short8*>(
          &Qb[xbase + (size_t)(q0 + wr + fm * 16 + lrow) * D_ + s * 32 + lk * 8]);
  floatx4 ao[2][4] = {};
  const int nkk = CAUSAL ? 2 * (qt + 1) : (S_ / 64);

  STAGE(0, 0);
  int cur = 0;
  for (int t = 0; t < nkk; ++t) {
    const int kk0 = t * 64;
    const bool maskt = CAUSAL && (kk0 + 64 > q0);
    if (t + 1 < nkk) {
      STAGE(cur ^ 1, t + 1);
      __builtin_amdgcn_sched_barrier(0);
      asm volatile("s_waitcnt vmcnt(5)" ::: "memory");  // cur's 5 done; next 5 in flight
    } else {
      __builtin_amdgcn_sched_barrier(0);
      asm volatile("s_waitcnt vmcnt(0)" ::: "memory");
    }
    __builtin_amdgcn_s_barrier();
    __builtin_amdgcn_sched_barrier(0);
    // QK^T swapped: mfma(KV, Q) -> C[kk][q]; lane holds 4 consecutive kk for q=lrow
#pragma unroll
    for (int kkf = 0; kkf < 4; ++kkf) {
      const int br = kkf * 16 + lrow;
      short8 b0 =
          *reinterpret_cast<const short8*>(&kvs[cur][br * 64 + ((lk ^ (br & 7)) << 3)]);
      short8 b1 =
          *reinterpret_cast<const short8*>(&kvs[cur][br * 64 + (((4 + lk) ^ (br & 7)) << 3)]);
      const floatx4 nl4 =
          *reinterpret_cast<const floatx4*>(&slnl[cur][w][kkf * 16 + lk * 4]);
      const int kkbase = kk0 + kkf * 16 + lk * 4;
#pragma unroll
      for (int fm = 0; fm < 2; ++fm) {
        floatx4 sf = nl4;  // acc pre-init with -log2(l) per kk row
        sf = __builtin_amdgcn_mfma_f32_16x16x32_bf16(b0, aq[fm][0], sf, 0, 0, 0);
        sf = __builtin_amdgcn_mfma_f32_16x16x32_bf16(b1, aq[fm][1], sf, 0, 0, 0);
        float p0 = EXP2V(sf[0]);
        float p1 = EXP2V(sf[1]);
        float p2 = EXP2V(sf[2]);
        float p3 = EXP2V(sf[3]);
        if (maskt) {
          const int qg = q0 + wr + fm * 16 + lrow;
          p0 = (kkbase + 0 <= qg) ? p0 : 0.0f;
          p1 = (kkbase + 1 <= qg) ? p1 : 0.0f;
          p2 = (kkbase + 2 <= qg) ? p2 : 0.0f;
          p3 = (kkbase + 3 <= qg) ? p3 : 0.0f;
        }
        unsigned int u0 = cvtpk_bf16(p0, p1);
        unsigned int u1 = cvtpk_bf16(p2, p3);
        const int rowq = fm * 16 + lrow;
        unsigned short* pb =
            &ps[w][rowq * 64 + ((((kkf << 1) + (lk >> 1)) ^ (lrow & 7)) << 3) +
                   ((lk & 1) << 2)];
        *reinterpret_cast<unsigned int*>(pb) = u0;
        *reinterpret_cast<unsigned int*>(pb + 2) = u1;
      }
    }
    short8 pa[2][2];
#pragma unroll
    for (int fm = 0; fm < 2; ++fm)
#pragma unroll
      for (int s2 = 0; s2 < 2; ++s2)
        pa[fm][s2] = *reinterpret_cast<const short8*>(
            &ps[w][(fm * 16 + lrow) * 64 + (((s2 * 4 + lk) ^ (lrow & 7)) << 3)]);
    __builtin_amdgcn_s_setprio(1);
#pragma unroll
    for (int dn = 0; dn < 4; ++dn) {
#pragma unroll
      for (int s2 = 0; s2 < 2; ++s2) {
        const int br2 = dn * 16 + lrow;
        short8 bv = *reinterpret_cast<const short8*>(
            &kvts[cur][br2 * 64 + (((s2 * 4 + lk) ^ (br2 & 7)) << 3)]);
#pragma unroll
        for (int fm = 0; fm < 2; ++fm)
          ao[fm][dn] =
              __builtin_amdgcn_mfma_f32_16x16x32_bf16(pa[fm][s2], bv, ao[fm][dn], 0, 0, 0);
      }
    }
    __builtin_amdgcn_s_setprio(0);
    __builtin_amdgcn_sched_barrier(0);
    __builtin_amdgcn_s_barrier();  // all waves done reading buf[cur] -> safe to restage
    __builtin_amdgcn_sched_barrier(0);
    cur ^= 1;
  }
#pragma unroll
  for (int fm = 0; fm < 2; ++fm)
#pragma unroll
    for (int dn = 0; dn < 4; ++dn)
#pragma unroll
      for (int r = 0; r < 4; ++r)
        Opre[xbase + (size_t)(q0 + wr + fm * 16 + lk * 4 + r) * D_ + dn * 16 + lrow] =
            ao[fm][dn][r];
}

// -------- residual + LayerNorm: one wave per row, float4, no barriers --------
template <bool WRITEBF, bool TWO, bool BIAS>
__global__ __launch_bounds__(256) void ln_kernel(const float* __restrict__ pre,
                                                 const float* __restrict__ pre2,
                                                 const float* __restrict__ bias,
                                                 const float* __restrict__ res,
                                                 const float* __restrict__ gam,
                                                 const float* __restrict__ bet,
                                                 float* __restrict__ outf,
                                                 unsigned short* __restrict__ outb) {
  const int w = threadIdx.x >> 6, l = threadIdx.x & 63;
  const int row = blockIdx.x * 4 + w;
  const size_t base = (size_t)row * D_;
  floatx4 v[3];
  float s = 0.0f;
#pragma unroll
  for (int j = 0; j < 3; ++j) {
    int i = j * 256 + l * 4;
    floatx4 t = *reinterpret_cast<const floatx4*>(&pre[base + i]);
    floatx4 rv = *reinterpret_cast<const floatx4*>(&res[base + i]);
#pragma unroll
    for (int e = 0; e < 4; ++e) t[e] += rv[e];
    if (TWO) {
      floatx4 t2 = *reinterpret_cast<const floatx4*>(&pre2[base + i]);
#pragma unroll
      for (int e = 0; e < 4; ++e) t[e] += t2[e];
    }
    if (BIAS) {
      floatx4 bv = *reinterpret_cast<const floatx4*>(&bias[i]);
#pragma unroll
      for (int e = 0; e < 4; ++e) t[e] += bv[e];
    }
    v[j] = t;
#pragma unroll
    for (int e = 0; e < 4; ++e) s += t[e];
  }
#pragma unroll
  for (int off = 32; off; off >>= 1) s += __shfl_xor(s, off, 64);
  const float mu = s * (1.0f / 768.0f);
  float vs = 0.0f;
#pragma unroll
  for (int j = 0; j < 3; ++j)
#pragma unroll
    for (int e = 0; e < 4; ++e) { float d = v[j][e] - mu; vs += d * d; }
#pragma unroll
  for (int off = 32; off; off >>= 1) vs += __shfl_xor(vs, off, 64);
  const float rstd = rsqrtf(vs * (1.0f / 768.0f) + 1e-5f);
#pragma unroll
  for (int j = 0; j < 3; ++j) {
    int i = j * 256 + l * 4;
    floatx4 gv = *reinterpret_cast<const floatx4*>(&gam[i]);
    floatx4 bev = *reinterpret_cast<const floatx4*>(&bet[i]);
    floatx4 o;
#pragma unroll
    for (int e = 0; e < 4; ++e) o[e] = (v[j][e] - mu) * rstd * gv[e] + bev[e];
    *reinterpret_cast<floatx4*>(&outf[base + i]) = o;
    if (WRITEBF) {
      ushort4v ob;
#pragma unroll
      for (int e = 0; e < 4; ++e) ob[e] = f2bf(o[e]);
      *reinterpret_cast<ushort4v*>(&outb[base + i]) = ob;
    }
  }
}

extern "C" void kernel_launch(void* const* d_in, const int* in_sizes, int n_in,
                              void* d_out, int out_size, void* d_ws, size_t ws_size,
                              hipStream_t stream) {
  const float* x = (const float*)d_in[0];
  const float* Wq1 = (const float*)d_in[2];
  const float* Wv1 = (const float*)d_in[3];
  const float* g1 = (const float*)d_in[4];
  const float* be1 = (const float*)d_in[5];
  const float* Wq2 = (const float*)d_in[6];
  const float* Wv2 = (const float*)d_in[7];
  const float* g2 = (const float*)d_in[8];
  const float* be2 = (const float*)d_in[9];
  const float* Wf1 = (const float*)d_in[10];
  const float* bf1 = (const float*)d_in[11];
  const float* Wf2 = (const float*)d_in[12];
  const float* bf2 = (const float*)d_in[13];
  const float* gf = (const float*)d_in[14];
  const float* bef = (const float*)d_in[15];

  char* ws = (char*)d_ws;
  size_t off = 0;
  auto alloc = [&](size_t bytes) -> void* {
    void* p = ws + off;
    off += (bytes + 255) & ~(size_t)255;
    return p;
  };
  unsigned short* xb = (unsigned short*)alloc((size_t)M_ * D_ * 2);
  unsigned short* qb = (unsigned short*)alloc((size_t)M_ * D_ * 2);
  unsigned short* kvb = (unsigned short*)alloc((size_t)M_ * D_ * 2);  // qb+kvb contiguous
  unsigned short* kvtb = (unsigned short*)alloc((size_t)BH_ * DH_ * S_ * 2);
  float* lnl = (float*)alloc((size_t)BH_ * S_ * 4);
  float* preA = (float*)alloc((size_t)M_ * D_ * 4);
  float* xcur = (float*)alloc((size_t)M_ * D_ * 4);
  unsigned short* hb = (unsigned short*)alloc((size_t)M_ * DFF_ * 2);
  unsigned short* wqv1t = (unsigned short*)alloc((size_t)D_ * 1536 * 2);
  unsigned short* wqv2t = (unsigned short*)alloc((size_t)D_ * 1536 * 2);
  unsigned short* wf1t = (unsigned short*)alloc((size_t)D_ * DFF_ * 2);
  unsigned short* wf2t = (unsigned short*)alloc((size_t)D_ * DFF_ * 2);
  float* preB = (float*)qb;  // FF2 split-K second half reuses dead qb+kvb
  if (off > ws_size) return;

  const dim3 blk(256);
  cvt_bf16<<<dim3((M_ * D_) / 1024), blk, 0, stream>>>(x, xb);
  wtrans<<<dim3(12, 12), blk, 0, stream>>>(Wq1, wqv1t, D_, D_);
  wtrans<<<dim3(12, 12), blk, 0, stream>>>(Wv1, wqv1t + (size_t)768 * 768, D_, D_);
  wtrans<<<dim3(12, 12), blk, 0, stream>>>(Wq2, wqv2t, D_, D_);
  wtrans<<<dim3(12, 12), blk, 0, stream>>>(Wv2, wqv2t + (size_t)768 * 768, D_, D_);
  wtrans<<<dim3(48, 12), blk, 0, stream>>>(Wf1, wf1t, D_, DFF_);
  wtrans<<<dim3(12, 48), blk, 0, stream>>>(Wf2, wf2t, DFF_, D_);

  const dim3 gqkv(24, 64);  // BN=64: 1536 blocks, 2-3 full dispatch waves
  const dim3 gkvt(S_ / 64, BH_);

  // ---- attention block 1 (causal) ----
  gemm128<3, 1, 64><<<gqkv, blk, 0, stream>>>(xb, wqv1t, nullptr, QSCALE, qb, kvb, M_, 1536,
                                              D_, D_);
  kvtrans<<<gkvt, blk, 0, stream>>>(kvb, kvtb);
  colsum<true><<<dim3(32 * BH_), blk, 0, stream>>>(qb, kvb, lnl);
  attnpv<true><<<dim3(16 * BH_), blk, 0, stream>>>(qb, kvb, kvtb, lnl, preA);
  ln_kernel<true, false, false><<<dim3(M_ / 4), blk, 0, stream>>>(preA, nullptr, nullptr, x, g1,
                                                                  be1, xcur, xb);

  // ---- attention block 2 (no mask) ----
  gemm128<3, 1, 64><<<gqkv, blk, 0, stream>>>(xb, wqv2t, nullptr, QSCALE, qb, kvb, M_, 1536,
                                              D_, D_);
  kvtrans<<<gkvt, blk, 0, stream>>>(kvb, kvtb);
  colsum<false><<<dim3(32 * BH_), blk, 0, stream>>>(qb, kvb, lnl);
  attnpv<false><<<dim3(16 * BH_), blk, 0, stream>>>(qb, kvb, kvtb, lnl, preA);
  ln_kernel<true, false, false><<<dim3(M_ / 4), blk, 0, stream>>>(preA, nullptr, nullptr, xcur,
                                                                  g2, be2, xcur, xb);

  // ---- feed-forward ----
  gemm128<1, 1, 128><<<dim3(24, 64), blk, 0, stream>>>(xb, wf1t, bf1, 1.0f, hb, nullptr, M_,
                                                       DFF_, D_, D_);
  gemm128<0, 0, 64><<<dim3(12, 64, 2), blk, 0, stream>>>(hb, wf2t, nullptr, 1.0f, preA, preB,
                                                         M_, D_, DFF_ / 2, DFF_);
  ln_kernel<false, true, true><<<dim3(M_ / 4), blk, 0, stream>>>(preA, preB, bf2, xcur, gf, bef,
                                                                 (float*)d_out, nullptr);
}

// Round 11
// 463.885 us; speedup vs baseline: 1.0298x; 1.0298x over previous
//
#include <hip/hip_runtime.h>

typedef __attribute__((ext_vector_type(8))) short short8;
typedef __attribute__((ext_vector_type(4))) float floatx4;
typedef __attribute__((ext_vector_type(4))) unsigned short ushort4v;

#define H_ 12
#define S_ 2048
#define D_ 768
#define DFF_ 3072
#define DH_ 64
#define BH_ 48
#define M_ 8192
// 0.125 (1/sqrt(64)) * log2(e): QK^T lands in log2-domain
#define QSCALE 0.180336880f

// HW exp2/log2 via compiler-known trans intrinsics (raw inline-asm v_exp raced -> NaN, r5).
#if defined(__has_builtin)
#if __has_builtin(__builtin_amdgcn_exp2f)
#define EXP2V(x) __builtin_amdgcn_exp2f(x)
#endif
#if __has_builtin(__builtin_amdgcn_logf)
#define LOG2V(x) __builtin_amdgcn_logf(x)
#endif
#endif
#ifndef EXP2V
#define EXP2V(x) exp2f(x)
#endif
#ifndef LOG2V
#define LOG2V(x) log2f(x)
#endif

__device__ __forceinline__ unsigned short f2bf(float f) {
  union { float f; unsigned int u; } a; a.f = f;
  return (unsigned short)((a.u + 0x7FFFu + ((a.u >> 16) & 1u)) >> 16);
}
__device__ __forceinline__ unsigned int cvtpk_bf16(float lo, float hi) {
  unsigned int u;
  asm("v_cvt_pk_bf16_f32 %0, %1, %2" : "=v"(u) : "v"(lo), "v"(hi));
  return u;
}

// async global->LDS. LDS base wave-uniform (HW adds lane*size).
__device__ __forceinline__ void glds16(const void* g, void* l) {
  __builtin_amdgcn_global_load_lds(
      (const __attribute__((address_space(1))) void*)(unsigned long long)(size_t)g,
      (__attribute__((address_space(3))) void*)(unsigned int)(size_t)l, 16, 0, 0);
}
__device__ __forceinline__ void glds4(const void* g, void* l) {
  __builtin_amdgcn_global_load_lds(
      (const __attribute__((address_space(1))) void*)(unsigned long long)(size_t)g,
      (__attribute__((address_space(3))) void*)(unsigned int)(size_t)l, 4, 0, 0);
}

// XCD-chunked bijective swizzle (nwg % 8 == 0).
__device__ __forceinline__ int swz8(int lin, int nwg) {
  return (lin & 7) * (nwg >> 3) + (lin >> 3);
}

// ---------------- fp32 -> bf16 convert ----------------
__global__ __launch_bounds__(256) void cvt_bf16(const float* __restrict__ in,
                                                unsigned short* __restrict__ out) {
  size_t i = ((size_t)blockIdx.x * 256 + threadIdx.x) * 4;
  floatx4 v = *reinterpret_cast<const floatx4*>(in + i);
  ushort4v o;
  o[0] = f2bf(v[0]); o[1] = f2bf(v[1]); o[2] = f2bf(v[2]); o[3] = f2bf(v[3]);
  *reinterpret_cast<ushort4v*>(out + i) = o;
}

// ---------------- weight transpose fp32[K][N] -> bf16[N][K] ----------------
__global__ __launch_bounds__(256) void wtrans(const float* __restrict__ W,
                                              unsigned short* __restrict__ Wt,
                                              int K, int N) {
  __shared__ float t[64][65];
  const int n0 = blockIdx.x * 64, k0 = blockIdx.y * 64;
  const int tid = threadIdx.x;
#pragma unroll
  for (int i = 0; i < 16; ++i) {
    int idx = tid + 256 * i;
    int kl = idx >> 6, nl = idx & 63;
    t[kl][nl] = W[(size_t)(k0 + kl) * N + n0 + nl];
  }
  __syncthreads();
#pragma unroll
  for (int i = 0; i < 16; ++i) {
    int idx = tid + 256 * i;
    int nl = idx >> 6, kl = idx & 63;
    Wt[(size_t)(n0 + nl) * K + k0 + kl] = f2bf(t[kl][nl]);
  }
}

// ---- per-head transpose + K-fragment pack ----
// KVTb[bh][d][kk] (V-transposed, as before) and kfb: fragment-major K buffer.
// kfb frag fi=kkf*2+s, lane l, short j = KV[kk0+kkf*16+(l&15)][s*32+(l>>4)*8+j]
// (exactly the value round-7's LDS path delivered to b0/b1).
__global__ __launch_bounds__(256) void kvtrans(const unsigned short* __restrict__ KVb,
                                               unsigned short* __restrict__ KVTb,
                                               unsigned short* __restrict__ kfb) {
  __shared__ unsigned short t[64][72];
  const int kt = blockIdx.x;
  const int kk0 = kt * 64;
  const int bh = blockIdx.y, b = bh / H_, h = bh % H_;
  const size_t xbase = ((size_t)b * S_) * D_ + h * DH_;
  const int tid = threadIdx.x;
#pragma unroll
  for (int i = 0; i < 16; ++i) {
    int idx = tid + 256 * i;
    int kl = idx >> 6, d = idx & 63;
    t[kl][d] = KVb[xbase + (size_t)(kk0 + kl) * D_ + d];
  }
  __syncthreads();
  const size_t tb = (size_t)bh * DH_ * S_;
#pragma unroll
  for (int i = 0; i < 16; ++i) {
    int idx = tid + 256 * i;
    int d = idx >> 6, kl = idx & 63;
    KVTb[tb + (size_t)d * S_ + kk0 + kl] = t[kl][d];
  }
  const size_t obase = ((size_t)bh * 32 + kt) * 4096;  // shorts
#pragma unroll
  for (int i = 0; i < 2; ++i) {
    int idx = tid + 256 * i;  // 0..511
    int fi = idx >> 6, ll = idx & 63;
    int kkf = fi >> 1, s = fi & 1;
    short8 v =
        *reinterpret_cast<const short8*>(&t[kkf * 16 + (ll & 15)][s * 32 + (ll >> 4) * 8]);
    *reinterpret_cast<short8*>(&kfb[obase + (size_t)fi * 512 + ll * 8]) = v;
  }
}

// ---------------- bf16 GEMM: C[M][N] = A[M][K] * Bt[N][K]^T (round-7 structure) ----------------
template <int EPI, int OUTBF>
__global__ __launch_bounds__(256, 2) void gemm128(const unsigned short* __restrict__ A,
                                                  const unsigned short* __restrict__ Bt,
                                                  const float* __restrict__ bias,
                                                  float scale, void* __restrict__ C0,
                                                  void* __restrict__ C1,
                                                  int M, int N, int K, int lda) {
  __shared__ unsigned short As[128 * 64];
  __shared__ unsigned short Bs[128 * 64];
  const int tid = threadIdx.x;
  const int l = tid & 63, w = tid >> 6;
  const int wm = w >> 1, wn = w & 1;
  const int lrow = l & 15, lk = l >> 4;
  int lin = (blockIdx.z * gridDim.y + blockIdx.y) * gridDim.x + blockIdx.x;
  int nwg = gridDim.x * gridDim.y * gridDim.z;
  int s = swz8(lin, nwg);
  int xt = s % gridDim.x;
  int rest = s / gridDim.x;
  int yt = rest % gridDim.y;
  int zt = rest / gridDim.y;
  const unsigned short* Ao = A + (size_t)zt * K;
  const unsigned short* Bo = Bt + (size_t)zt * K;
  const int m0 = yt * 128, n0 = xt * 128;
  floatx4 acc[4][4] = {};
  for (int k0 = 0; k0 < K; k0 += 64) {
    __syncthreads();
#pragma unroll
    for (int i = 0; i < 4; ++i) {
      int idx = w * 64 + i * 256 + l;
      int row = idx >> 3, c8 = idx & 7;
      int sc = (c8 ^ (row & 7)) << 3;
      glds16(Ao + (size_t)(m0 + row) * lda + k0 + sc, As + (size_t)(w * 64 + i * 256) * 8);
      glds16(Bo + (size_t)(n0 + row) * lda + k0 + sc, Bs + (size_t)(w * 64 + i * 256) * 8);
    }
    __syncthreads();
#pragma unroll
    for (int ks = 0; ks < 2; ++ks) {
      short8 af[4], bfr[4];
#pragma unroll
      for (int f = 0; f < 4; ++f) {
        int ar = wm * 64 + f * 16 + lrow;
        af[f] = *reinterpret_cast<const short8*>(
            &As[ar * 64 + (((ks * 4 + lk) ^ (ar & 7)) << 3)]);
        int br = wn * 64 + f * 16 + lrow;
        bfr[f] = *reinterpret_cast<const short8*>(
            &Bs[br * 64 + (((ks * 4 + lk) ^ (br & 7)) << 3)]);
      }
#pragma unroll
      for (int fm = 0; fm < 4; ++fm)
#pragma unroll
        for (int fn = 0; fn < 4; ++fn)
          acc[fm][fn] =
              __builtin_amdgcn_mfma_f32_16x16x32_bf16(af[fm], bfr[fn], acc[fm][fn], 0, 0, 0);
    }
  }
#pragma unroll
  for (int fm = 0; fm < 4; ++fm) {
#pragma unroll
    for (int fn = 0; fn < 4; ++fn) {
      int col = n0 + wn * 64 + fn * 16 + lrow;
#pragma unroll
      for (int r = 0; r < 4; ++r) {
        int row = m0 + wm * 64 + fm * 16 + lk * 4 + r;
        float v = acc[fm][fn][r];
        if (EPI == 3) {
          if (col < 768)
            ((unsigned short*)C0)[(size_t)row * 768 + col] = f2bf(v * scale);
          else
            ((unsigned short*)C1)[(size_t)row * 768 + col - 768] = f2bf(v);
        } else {
          v = v * scale + ((EPI > 0) ? bias[col] : 0.0f);
          if (EPI == 1) v = fmaxf(v, 0.0f);
          void* Cz = zt ? C1 : C0;
          if (OUTBF) ((unsigned short*)Cz)[(size_t)row * N + col] = f2bf(v);
          else ((float*)Cz)[(size_t)row * N + col] = v;
        }
      }
    }
  }
}

// ------ column softmax denominators (log2 domain): lnl[k] = -log2(sum_q 2^w2[q,k]) ------
// K fragments straight from kfb (no LDS staging / barrier).
template <bool CAUSAL>
__global__ __launch_bounds__(256, 4) void colsum(const unsigned short* __restrict__ Qb,
                                                 const unsigned short* __restrict__ kfb,
                                                 float* __restrict__ lnl) {
  __shared__ float lred[4][64];
  const int tid = threadIdx.x;
  const int l = tid & 63, w = tid >> 6;
  const int lrow = l & 15, lk = l >> 4;
  const int sw = swz8(blockIdx.x, 32 * BH_);
  const int bh = sw >> 5, kt = sw & 31;
  const int kk0 = kt * 64;
  const int b = bh / H_, h = bh % H_;
  const size_t xbase = ((size_t)b * S_) * D_ + h * DH_;
  const unsigned short* kfT = kfb + ((size_t)bh * 32 + kt) * 4096;
  short8 bkv[4][2];
#pragma unroll
  for (int kkf = 0; kkf < 4; ++kkf)
#pragma unroll
    for (int s = 0; s < 2; ++s)
      bkv[kkf][s] =
          *reinterpret_cast<const short8*>(&kfT[(size_t)(kkf * 2 + s) * 512 + l * 8]);
  float lrun[4] = {0.0f, 0.0f, 0.0f, 0.0f};
  const int qbase = CAUSAL ? kk0 : 0;
  const int ntiles = (S_ - qbase) >> 4;
  // software-pipelined Q loads (one tile ahead)
  short8 aqn[2];
  if (w < ntiles) {
    const int q0 = qbase + w * 16;
#pragma unroll
    for (int s = 0; s < 2; ++s)
      aqn[s] = *reinterpret_cast<const short8*>(
          &Qb[xbase + (size_t)(q0 + lrow) * D_ + s * 32 + lk * 8]);
  }
  for (int t = w; t < ntiles; t += 4) {
    const int q0 = qbase + t * 16;
    const bool maskt = CAUSAL && (q0 < kk0 + 64);
    short8 aq0 = aqn[0], aq1 = aqn[1];
    if (t + 4 < ntiles) {
      const int qn = qbase + (t + 4) * 16;
#pragma unroll
      for (int s = 0; s < 2; ++s)
        aqn[s] = *reinterpret_cast<const short8*>(
            &Qb[xbase + (size_t)(qn + lrow) * D_ + s * 32 + lk * 8]);
    }
#pragma unroll
    for (int kkf = 0; kkf < 4; ++kkf) {
      floatx4 sf = {};
      sf = __builtin_amdgcn_mfma_f32_16x16x32_bf16(aq0, bkv[kkf][0], sf, 0, 0, 0);
      sf = __builtin_amdgcn_mfma_f32_16x16x32_bf16(aq1, bkv[kkf][1], sf, 0, 0, 0);
      const int kkg = kk0 + kkf * 16 + lrow;
      float lacc = 0.0f;
      if (maskt) {
#pragma unroll
        for (int r = 0; r < 4; ++r) {
          int qg = q0 + lk * 4 + r;
          lacc += (kkg <= qg) ? EXP2V(sf[r]) : 0.0f;
        }
      } else {
#pragma unroll
        for (int r = 0; r < 4; ++r) lacc += EXP2V(sf[r]);
      }
      lrun[kkf] += lacc;
    }
  }
#pragma unroll
  for (int kkf = 0; kkf < 4; ++kkf) {
    float lv = lrun[kkf];
    lv += __shfl_xor(lv, 16, 64);
    lv += __shfl_xor(lv, 32, 64);
    if (l < 16) lred[w][kkf * 16 + l] = lv;
  }
  __syncthreads();
  if (tid < 64) {
    float lv = lred[0][tid] + lred[1][tid] + lred[2][tid] + lred[3][tid];
    lnl[(size_t)bh * S_ + kk0 + tid] = -LOG2V(lv);  // negated: attnpv acc-init uses it raw
  }
}

// ---- attention PV: K fragments from kfb (registers, L1-shared across waves);
// V+lnl double-buffered in LDS with counted vmcnt; P path identical to round 7. ----
template <bool CAUSAL>
__global__ __launch_bounds__(256, 3) void attnpv(const unsigned short* __restrict__ Qb,
                                                 const unsigned short* __restrict__ kfb,
                                                 const unsigned short* __restrict__ KVTb,
                                                 const float* __restrict__ lnl,
                                                 float* __restrict__ Opre) {
  __shared__ unsigned short kvts[2][64 * 64];
  __shared__ float slnl[2][4][64];
  __shared__ unsigned short ps[4][32 * 64];
  const int tid = threadIdx.x;
  const int l = tid & 63, w = tid >> 6;
  const int lrow = l & 15, lk = l >> 4;
  const int sw = swz8(blockIdx.x, 16 * BH_);
  const int bh = sw >> 4, qtr = sw & 15;
  const int qt = CAUSAL ? (15 - qtr) : qtr;  // heavy blocks dispatch first
  const int q0 = qt * 128;
  const int wr = w * 32;
  const int b = bh / H_, h = bh % H_;
  const size_t xbase = ((size_t)b * S_) * D_ + h * DH_;
  const size_t tbase = (size_t)bh * DH_ * S_;
  const float* lnlb = lnl + (size_t)bh * S_;
  const unsigned short* kfB = kfb + (size_t)bh * 32 * 4096;

  // exactly 3 VMEM ops per STAGE per thread: 2 kvts + 1 slnl
  auto STAGE = [&](int buf, int t) {
    const int kk0 = t * 64;
#pragma unroll
    for (int i = 0; i < 2; ++i) {
      int idx = w * 64 + i * 256 + l;
      int row = idx >> 3, c8 = idx & 7;
      int sc = (c8 ^ (row & 7)) << 3;
      glds16(KVTb + tbase + (size_t)row * S_ + kk0 + sc,
             &kvts[buf][(size_t)(w * 64 + i * 256) * 8]);
    }
    glds4(lnlb + kk0 + l, &slnl[buf][w][0]);
  };

  short8 aq[2][2];
#pragma unroll
  for (int fm = 0; fm < 2; ++fm)
#pragma unroll
    for (int s = 0; s < 2; ++s)
      aq[fm][s] = *reinterpret_cast<const short8*>(
          &Qb[xbase + (size_t)(q0 + wr + fm * 16 + lrow) * D_ + s * 32 + lk * 8]);
  floatx4 ao[2][4] = {};
  const int nkk = CAUSAL ? 2 * (qt + 1) : (S_ / 64);

  STAGE(0, 0);
  int cur = 0;
  for (int t = 0; t < nkk; ++t) {
    const int kk0 = t * 64;
    const bool maskt = CAUSAL && (kk0 + 64 > q0);
    // current tile's K fragments from kfb: 8 coalesced b128 loads (L1 serves 3/4 waves)
    short8 kc[8];
#pragma unroll
    for (int fi = 0; fi < 8; ++fi)
      kc[fi] =
          *reinterpret_cast<const short8*>(&kfB[((size_t)t * 8 + fi) * 512 + l * 8]);
    if (t + 1 < nkk) {
      STAGE(cur ^ 1, t + 1);
      __builtin_amdgcn_sched_barrier(0);
      // outstanding: 8 kc + 3 next-stage; retire the 3 cur-stage ops issued last iter
      asm volatile("s_waitcnt vmcnt(11)" ::: "memory");
    } else {
      __builtin_amdgcn_sched_barrier(0);
      asm volatile("s_waitcnt vmcnt(8)" ::: "memory");  // only 8 kc may remain in flight
    }
    __builtin_amdgcn_s_barrier();
    __builtin_amdgcn_sched_barrier(0);
    // QK^T swapped: mfma(KV, Q) -> C[kk][q]; lane holds 4 consecutive kk for q=lrow
#pragma unroll
    for (int kkf = 0; kkf < 4; ++kkf) {
      const floatx4 nl4 =
          *reinterpret_cast<const floatx4*>(&slnl[cur][w][kkf * 16 + lk * 4]);
      const int kkbase = kk0 + kkf * 16 + lk * 4;
#pragma unroll
      for (int fm = 0; fm < 2; ++fm) {
        floatx4 sf = nl4;  // acc pre-init with -log2(l) per kk row
        sf = __builtin_amdgcn_mfma_f32_16x16x32_bf16(kc[kkf * 2 + 0], aq[fm][0], sf, 0, 0, 0);
        sf = __builtin_amdgcn_mfma_f32_16x16x32_bf16(kc[kkf * 2 + 1], aq[fm][1], sf, 0, 0, 0);
        float p0 = EXP2V(sf[0]);
        float p1 = EXP2V(sf[1]);
        float p2 = EXP2V(sf[2]);
        float p3 = EXP2V(sf[3]);
        if (maskt) {
          const int qg = q0 + wr + fm * 16 + lrow;
          p0 = (kkbase + 0 <= qg) ? p0 : 0.0f;
          p1 = (kkbase + 1 <= qg) ? p1 : 0.0f;
          p2 = (kkbase + 2 <= qg) ? p2 : 0.0f;
          p3 = (kkbase + 3 <= qg) ? p3 : 0.0f;
        }
        unsigned int u0 = cvtpk_bf16(p0, p1);
        unsigned int u1 = cvtpk_bf16(p2, p3);
        const int rowq = fm * 16 + lrow;
        unsigned short* pb =
            &ps[w][rowq * 64 + ((((kkf << 1) + (lk >> 1)) ^ (lrow & 7)) << 3) +
                   ((lk & 1) << 2)];
        *reinterpret_cast<unsigned int*>(pb) = u0;
        *reinterpret_cast<unsigned int*>(pb + 2) = u1;
      }
    }
    short8 pa[2][2];
#pragma unroll
    for (int fm = 0; fm < 2; ++fm)
#pragma unroll
      for (int s2 = 0; s2 < 2; ++s2)
        pa[fm][s2] = *reinterpret_cast<const short8*>(
            &ps[w][(fm * 16 + lrow) * 64 + (((s2 * 4 + lk) ^ (lrow & 7)) << 3)]);
    __builtin_amdgcn_s_setprio(1);
#pragma unroll
    for (int dn = 0; dn < 4; ++dn) {
#pragma unroll
      for (int s2 = 0; s2 < 2; ++s2) {
        const int br2 = dn * 16 + lrow;
        short8 bv = *reinterpret_cast<const short8*>(
            &kvts[cur][br2 * 64 + (((s2 * 4 + lk) ^ (br2 & 7)) << 3)]);
#pragma unroll
        for (int fm = 0; fm < 2; ++fm)
          ao[fm][dn] =
              __builtin_amdgcn_mfma_f32_16x16x32_bf16(pa[fm][s2], bv, ao[fm][dn], 0, 0, 0);
      }
    }
    __builtin_amdgcn_s_setprio(0);
    __builtin_amdgcn_sched_barrier(0);
    __builtin_amdgcn_s_barrier();  // all waves done reading buf[cur] -> safe to restage
    __builtin_amdgcn_sched_barrier(0);
    cur ^= 1;
  }
#pragma unroll
  for (int fm = 0; fm < 2; ++fm)
#pragma unroll
    for (int dn = 0; dn < 4; ++dn)
#pragma unroll
      for (int r = 0; r < 4; ++r)
        Opre[xbase + (size_t)(q0 + wr + fm * 16 + lk * 4 + r) * D_ + dn * 16 + lrow] =
            ao[fm][dn][r];
}

// -------- residual + LayerNorm: one wave per row, float4, no barriers --------
template <bool WRITEBF, bool TWO, bool BIAS>
__global__ __launch_bounds__(256) void ln_kernel(const float* __restrict__ pre,
                                                 const float* __restrict__ pre2,
                                                 const float* __restrict__ bias,
                                                 const float* __restrict__ res,
                                                 const float* __restrict__ gam,
                                                 const float* __restrict__ bet,
                                                 float* __restrict__ outf,
                                                 unsigned short* __restrict__ outb) {
  const int w = threadIdx.x >> 6, l = threadIdx.x & 63;
  const int row = blockIdx.x * 4 + w;
  const size_t base = (size_t)row * D_;
  floatx4 v[3];
  float s = 0.0f;
#pragma unroll
  for (int j = 0; j < 3; ++j) {
    int i = j * 256 + l * 4;
    floatx4 t = *reinterpret_cast<const floatx4*>(&pre[base + i]);
    floatx4 rv = *reinterpret_cast<const floatx4*>(&res[base + i]);
#pragma unroll
    for (int e = 0; e < 4; ++e) t[e] += rv[e];
    if (TWO) {
      floatx4 t2 = *reinterpret_cast<const floatx4*>(&pre2[base + i]);
#pragma unroll
      for (int e = 0; e < 4; ++e) t[e] += t2[e];
    }
    if (BIAS) {
      floatx4 bv = *reinterpret_cast<const floatx4*>(&bias[i]);
#pragma unroll
      for (int e = 0; e < 4; ++e) t[e] += bv[e];
    }
    v[j] = t;
#pragma unroll
    for (int e = 0; e < 4; ++e) s += t[e];
  }
#pragma unroll
  for (int off = 32; off; off >>= 1) s += __shfl_xor(s, off, 64);
  const float mu = s * (1.0f / 768.0f);
  float vs = 0.0f;
#pragma unroll
  for (int j = 0; j < 3; ++j)
#pragma unroll
    for (int e = 0; e < 4; ++e) { float d = v[j][e] - mu; vs += d * d; }
#pragma unroll
  for (int off = 32; off; off >>= 1) vs += __shfl_xor(vs, off, 64);
  const float rstd = rsqrtf(vs * (1.0f / 768.0f) + 1e-5f);
#pragma unroll
  for (int j = 0; j < 3; ++j) {
    int i = j * 256 + l * 4;
    floatx4 gv = *reinterpret_cast<const floatx4*>(&gam[i]);
    floatx4 bev = *reinterpret_cast<const floatx4*>(&bet[i]);
    floatx4 o;
#pragma unroll
    for (int e = 0; e < 4; ++e) o[e] = (v[j][e] - mu) * rstd * gv[e] + bev[e];
    *reinterpret_cast<floatx4*>(&outf[base + i]) = o;
    if (WRITEBF) {
      ushort4v ob;
#pragma unroll
      for (int e = 0; e < 4; ++e) ob[e] = f2bf(o[e]);
      *reinterpret_cast<ushort4v*>(&outb[base + i]) = ob;
    }
  }
}

extern "C" void kernel_launch(void* const* d_in, const int* in_sizes, int n_in,
                              void* d_out, int out_size, void* d_ws, size_t ws_size,
                              hipStream_t stream) {
  const float* x = (const float*)d_in[0];
  const float* Wq1 = (const float*)d_in[2];
  const float* Wv1 = (const float*)d_in[3];
  const float* g1 = (const float*)d_in[4];
  const float* be1 = (const float*)d_in[5];
  const float* Wq2 = (const float*)d_in[6];
  const float* Wv2 = (const float*)d_in[7];
  const float* g2 = (const float*)d_in[8];
  const float* be2 = (const float*)d_in[9];
  const float* Wf1 = (const float*)d_in[10];
  const float* bf1 = (const float*)d_in[11];
  const float* Wf2 = (const float*)d_in[12];
  const float* bf2 = (const float*)d_in[13];
  const float* gf = (const float*)d_in[14];
  const float* bef = (const float*)d_in[15];

  char* ws = (char*)d_ws;
  size_t off = 0;
  auto alloc = [&](size_t bytes) -> void* {
    void* p = ws + off;
    off += (bytes + 255) & ~(size_t)255;
    return p;
  };
  unsigned short* xb = (unsigned short*)alloc((size_t)M_ * D_ * 2);
  unsigned short* qb = (unsigned short*)alloc((size_t)M_ * D_ * 2);
  unsigned short* kvb = (unsigned short*)alloc((size_t)M_ * D_ * 2);  // qb+kvb contiguous
  unsigned short* kvtb = (unsigned short*)alloc((size_t)BH_ * DH_ * S_ * 2);
  unsigned short* kfb = (unsigned short*)alloc((size_t)BH_ * 32 * 4096 * 2);
  float* lnl = (float*)alloc((size_t)BH_ * S_ * 4);
  float* preA = (float*)alloc((size_t)M_ * D_ * 4);
  float* xcur = (float*)alloc((size_t)M_ * D_ * 4);
  unsigned short* hb = (unsigned short*)alloc((size_t)M_ * DFF_ * 2);
  unsigned short* wqv1t = (unsigned short*)alloc((size_t)D_ * 1536 * 2);
  unsigned short* wqv2t = (unsigned short*)alloc((size_t)D_ * 1536 * 2);
  unsigned short* wf1t = (unsigned short*)alloc((size_t)D_ * DFF_ * 2);
  unsigned short* wf2t = (unsigned short*)alloc((size_t)D_ * DFF_ * 2);
  float* preB = (float*)qb;  // FF2 split-K second half reuses dead qb+kvb
  if (off > ws_size) return;

  const dim3 blk(256);
  cvt_bf16<<<dim3((M_ * D_) / 1024), blk, 0, stream>>>(x, xb);
  wtrans<<<dim3(12, 12), blk, 0, stream>>>(Wq1, wqv1t, D_, D_);
  wtrans<<<dim3(12, 12), blk, 0, stream>>>(Wv1, wqv1t + (size_t)768 * 768, D_, D_);
  wtrans<<<dim3(12, 12), blk, 0, stream>>>(Wq2, wqv2t, D_, D_);
  wtrans<<<dim3(12, 12), blk, 0, stream>>>(Wv2, wqv2t + (size_t)768 * 768, D_, D_);
  wtrans<<<dim3(48, 12), blk, 0, stream>>>(Wf1, wf1t, D_, DFF_);
  wtrans<<<dim3(12, 48), blk, 0, stream>>>(Wf2, wf2t, DFF_, D_);

  const dim3 gqkv(12, 64);
  const dim3 gkvt(S_ / 64, BH_);

  // ---- attention block 1 (causal) ----
  gemm128<3, 1><<<gqkv, blk, 0, stream>>>(xb, wqv1t, nullptr, QSCALE, qb, kvb, M_, 1536, D_, D_);
  kvtrans<<<gkvt, blk, 0, stream>>>(kvb, kvtb, kfb);
  colsum<true><<<dim3(32 * BH_), blk, 0, stream>>>(qb, kfb, lnl);
  attnpv<true><<<dim3(16 * BH_), blk, 0, stream>>>(qb, kfb, kvtb, lnl, preA);
  ln_kernel<true, false, false><<<dim3(M_ / 4), blk, 0, stream>>>(preA, nullptr, nullptr, x, g1,
                                                                  be1, xcur, xb);

  // ---- attention block 2 (no mask) ----
  gemm128<3, 1><<<gqkv, blk, 0, stream>>>(xb, wqv2t, nullptr, QSCALE, qb, kvb, M_, 1536, D_, D_);
  kvtrans<<<gkvt, blk, 0, stream>>>(kvb, kvtb, kfb);
  colsum<false><<<dim3(32 * BH_), blk, 0, stream>>>(qb, kfb, lnl);
  attnpv<false><<<dim3(16 * BH_), blk, 0, stream>>>(qb, kfb, kvtb, lnl, preA);
  ln_kernel<true, false, false><<<dim3(M_ / 4), blk, 0, stream>>>(preA, nullptr, nullptr, xcur,
                                                                  g2, be2, xcur, xb);

  // ---- feed-forward ----
  gemm128<1, 1><<<dim3(24, 64), blk, 0, stream>>>(xb, wf1t, bf1, 1.0f, hb, nullptr, M_, DFF_,
                                                  D_, D_);
  gemm128<0, 0><<<dim3(6, 64, 2), blk, 0, stream>>>(hb, wf2t, nullptr, 1.0f, preA, preB, M_, D_,
                                                    DFF_ / 2, DFF_);
  ln_kernel<false, true, true><<<dim3(M_ / 4), blk, 0, stream>>>(preA, preB, bf2, xcur, gf, bef,
                                                                 (float*)d_out, nullptr);
}